// Round 12
// baseline (569.968 us; speedup 1.0000x reference)
//
#include <hip/hip_runtime.h>

// B=4, H=16, L=1024, D=1024, DH=64, P=1024
// ws: Qhi,Qlo (pre-scaled by 1/8), Khi,Klo bf16 [B,H,L,64]; Vt bf16 [B,H,64,L];
//     Xhi,Xlo bf16 [4096,1024]; Wthi,Wtlo bf16 [3072,1024]; de16 bf16 [2047,64]

#define SCALE 0.125f  // 1/sqrt(64)

typedef __attribute__((ext_vector_type(8))) short bf16x8;
typedef __attribute__((ext_vector_type(4))) float f32x4;
#define MFMA16(a, b, c) __builtin_amdgcn_mfma_f32_16x16x32_bf16(a, b, c, 0, 0, 0)

__device__ __forceinline__ unsigned short f2bf(float x) {
    unsigned u = __builtin_bit_cast(unsigned, x);
    return (unsigned short)((u + 0x7FFFu + ((u >> 16) & 1u)) >> 16);  // RNE
}
__device__ __forceinline__ float bf2f(unsigned short h) {
    unsigned u = ((unsigned)h) << 16;
    return __builtin_bit_cast(float, u);
}

// ---------------- X fp32 -> hi/lo bf16 ----------------
__global__ __launch_bounds__(256) void conv_x(const float* __restrict__ x,
                                              unsigned short* __restrict__ xhi,
                                              unsigned short* __restrict__ xlo)
{
    size_t gid = (size_t)blockIdx.x * 256 + threadIdx.x;
    const float4* s = (const float4*)(x + gid * 8);
    float4 a = s[0], b = s[1];
    float v[8] = {a.x, a.y, a.z, a.w, b.x, b.y, b.z, b.w};
    unsigned hi[4], lo[4];
#pragma unroll
    for (int i = 0; i < 4; ++i) {
        unsigned short h0 = f2bf(v[2 * i]), h1 = f2bf(v[2 * i + 1]);
        hi[i] = (unsigned)h0 | ((unsigned)h1 << 16);
        unsigned short g0 = f2bf(v[2 * i] - bf2f(h0)), g1 = f2bf(v[2 * i + 1] - bf2f(h1));
        lo[i] = (unsigned)g0 | ((unsigned)g1 << 16);
    }
    *(uint4*)&xhi[gid * 8] = make_uint4(hi[0], hi[1], hi[2], hi[3]);
    *(uint4*)&xlo[gid * 8] = make_uint4(lo[0], lo[1], lo[2], lo[3]);
}

// ---------------- W [k][n] fp32 -> Wt [n + which*1024][k] hi/lo bf16 ----------------
__global__ __launch_bounds__(256) void conv_w(const float* __restrict__ Wq,
                                              const float* __restrict__ Wk,
                                              const float* __restrict__ Wv,
                                              unsigned short* __restrict__ wthi,
                                              unsigned short* __restrict__ wtlo)
{
    __shared__ float T[64][68];
    const int which = blockIdx.z;
    const float* W = which == 0 ? Wq : which == 1 ? Wk : Wv;
    const int k0 = blockIdx.y * 64, n0 = blockIdx.x * 64;
    const int ty = threadIdx.x >> 4, tx = threadIdx.x & 15;
#pragma unroll
    for (int i = 0; i < 4; ++i) {
        float4 v = *(const float4*)&W[(size_t)(k0 + ty * 4 + i) * 1024 + n0 + tx * 4];
        T[ty * 4 + i][tx * 4 + 0] = v.x;
        T[ty * 4 + i][tx * 4 + 1] = v.y;
        T[ty * 4 + i][tx * 4 + 2] = v.z;
        T[ty * 4 + i][tx * 4 + 3] = v.w;
    }
    __syncthreads();
#pragma unroll
    for (int i = 0; i < 4; ++i) {
        int n = n0 + ty * 4 + i;
        unsigned hi[2], lo[2];
#pragma unroll
        for (int p = 0; p < 2; ++p) {
            float v0 = T[tx * 4 + 2 * p][ty * 4 + i];
            float v1 = T[tx * 4 + 2 * p + 1][ty * 4 + i];
            unsigned short h0 = f2bf(v0), h1 = f2bf(v1);
            hi[p] = (unsigned)h0 | ((unsigned)h1 << 16);
            unsigned short g0 = f2bf(v0 - bf2f(h0)), g1 = f2bf(v1 - bf2f(h1));
            lo[p] = (unsigned)g0 | ((unsigned)g1 << 16);
        }
        size_t dst = (size_t)(which * 1024 + n) * 1024 + k0 + tx * 4;
        *(uint2*)&wthi[dst] = make_uint2(hi[0], hi[1]);
        *(uint2*)&wtlo[dst] = make_uint2(lo[0], lo[1]);
    }
}

// ---------------- dist_emb fp32 -> bf16 ----------------
__global__ __launch_bounds__(256) void conv_de(const float* __restrict__ de,
                                               unsigned short* __restrict__ de16)
{
    int gid = blockIdx.x * 256 + threadIdx.x;
    if (gid >= 16376) return;
    const float4* s = (const float4*)(de + gid * 8);
    float4 a = s[0], c = s[1];
    uint4 p;
    p.x = (unsigned)f2bf(a.x) | ((unsigned)f2bf(a.y) << 16);
    p.y = (unsigned)f2bf(a.z) | ((unsigned)f2bf(a.w) << 16);
    p.z = (unsigned)f2bf(c.x) | ((unsigned)f2bf(c.y) << 16);
    p.w = (unsigned)f2bf(c.z) | ((unsigned)f2bf(c.w) << 16);
    *(uint4*)&de16[gid * 8] = p;
}

// ---------------- fused QKV projection: split-bf16 MFMA GEMM (unchanged) ----------------
__global__ __launch_bounds__(256, 2) void qkv_gemm(
    const unsigned short* __restrict__ Xhi, const unsigned short* __restrict__ Xlo,
    const unsigned short* __restrict__ Wthi, const unsigned short* __restrict__ Wtlo,
    const float* __restrict__ bq, const float* __restrict__ bk, const float* __restrict__ bv,
    unsigned short* __restrict__ Qhi, unsigned short* __restrict__ Qlo,
    unsigned short* __restrict__ Khi, unsigned short* __restrict__ Klo,
    unsigned short* __restrict__ Vt)
{
    __shared__ __align__(16) unsigned short AhiS[128 * 64];
    __shared__ __align__(16) unsigned short AloS[128 * 64];
    __shared__ __align__(16) unsigned short BhiS[128 * 64];
    __shared__ __align__(16) unsigned short BloS[128 * 64];

    const int tid = threadIdx.x;
    const int wave = tid >> 6, lane = tid & 63;
    const int lr = lane & 15, lg = lane >> 4;
    const int wr = wave >> 1, wc = wave & 1;
    const int m0 = blockIdx.y * 128, n0 = blockIdx.x * 128;

    const f32x4 fzero = {0.f, 0.f, 0.f, 0.f};
    f32x4 acc[4][4];
#pragma unroll
    for (int i = 0; i < 4; ++i)
#pragma unroll
        for (int j = 0; j < 4; ++j) acc[i][j] = fzero;

    for (int k0 = 0; k0 < 1024; k0 += 64) {
        __syncthreads();
#pragma unroll
        for (int t = 0; t < 4; ++t) {
            int idx = tid + t * 256;
            int r = idx >> 3, u = idx & 7;
            int us = u ^ (r & 7);
            *(uint4*)&AhiS[r * 64 + us * 8] = *(const uint4*)&Xhi[(size_t)(m0 + r) * 1024 + k0 + u * 8];
            *(uint4*)&AloS[r * 64 + us * 8] = *(const uint4*)&Xlo[(size_t)(m0 + r) * 1024 + k0 + u * 8];
            *(uint4*)&BhiS[r * 64 + us * 8] = *(const uint4*)&Wthi[(size_t)(n0 + r) * 1024 + k0 + u * 8];
            *(uint4*)&BloS[r * 64 + us * 8] = *(const uint4*)&Wtlo[(size_t)(n0 + r) * 1024 + k0 + u * 8];
        }
        __syncthreads();
#pragma unroll
        for (int kh = 0; kh < 2; ++kh) {
            bf16x8 ah[4], al[4], bh[4], bl[4];
#pragma unroll
            for (int i = 0; i < 4; ++i) {
                int mrow = wr * 64 + i * 16 + lr;
                int usa = (kh * 4 + lg) ^ (mrow & 7);
                ah[i] = *(const bf16x8*)&AhiS[mrow * 64 + usa * 8];
                al[i] = *(const bf16x8*)&AloS[mrow * 64 + usa * 8];
                int nrow = wc * 64 + i * 16 + lr;
                int usb = (kh * 4 + lg) ^ (nrow & 7);
                bh[i] = *(const bf16x8*)&BhiS[nrow * 64 + usb * 8];
                bl[i] = *(const bf16x8*)&BloS[nrow * 64 + usb * 8];
            }
#pragma unroll
            for (int am = 0; am < 4; ++am)
#pragma unroll
                for (int bn = 0; bn < 4; ++bn) {
                    acc[am][bn] = MFMA16(ah[am], bh[bn], acc[am][bn]);
                    acc[am][bn] = MFMA16(al[am], bh[bn], acc[am][bn]);
                    acc[am][bn] = MFMA16(ah[am], bl[bn], acc[am][bn]);
                }
        }
    }

    const int which = n0 >> 10;
    const float* bsel = which == 0 ? bq : which == 1 ? bk : bv;
#pragma unroll
    for (int bn = 0; bn < 4; ++bn) {
        int n_g = n0 + wc * 64 + bn * 16 + lr;
        float bias = bsel[n_g & 1023];
        int hh = (n_g >> 6) & 15, d = n_g & 63;
#pragma unroll
        for (int am = 0; am < 4; ++am) {
#pragma unroll
            for (int reg = 0; reg < 4; ++reg) {
                int m_g = m0 + wr * 64 + am * 16 + lg * 4 + reg;
                int bb = m_g >> 10, l = m_g & 1023;
                float v = acc[am][bn][reg] + bias;
                if (which == 2) {
                    Vt[(((size_t)bb * 16 + hh) * 64 + d) * 1024 + l] = f2bf(v);
                } else {
                    if (which == 0) v *= SCALE;   // pre-scale Q (exact pow2)
                    size_t dst = (((size_t)bb * 16 + hh) * 1024 + l) * 64 + d;
                    unsigned short hi = f2bf(v);
                    unsigned short lo = f2bf(v - bf2f(hi));
                    if (which == 0) { Qhi[dst] = hi; Qlo[dst] = lo; }
                    else            { Khi[dst] = hi; Klo[dst] = lo; }
                }
            }
        }
    }
}

// ---------------- MFMA fused attention: NO K/V LDS staging (all fragments from L2) ----
// 256 thr / 4 waves / QBLK=64. LDS only: C/D band exchange (double-buffered, the one
// cross-wave structure) + wave-private P transpose buffer. 40 KB -> 4 blocks/CU
// (4 waves/SIMD, 2x round 7). ONE barrier per KV tile.
// Hazards: bb[cur] read(iter i) -> next write is iter i+2, ordered by barrier(i+1).
// PS is wave-private (each wave writes & reads only rows [w*16, w*16+16)) — intra-wave
// lgkmcnt ordering suffices, no barrier. No long-lived prefetch regs (r8/r9/r11 lesson).
__global__ __launch_bounds__(256, 4) void attn_kernel(
    const unsigned short* __restrict__ Qhi, const unsigned short* __restrict__ Qlo,
    const unsigned short* __restrict__ Khi, const unsigned short* __restrict__ Klo,
    const unsigned short* __restrict__ Vt,  const unsigned short* __restrict__ de16,
    const float* __restrict__ mask, float* __restrict__ out)
{
    __shared__ unsigned int bbS[2][64 * 64];               // 32 KB [l][r]: lo=C, hi=D
    __shared__ __align__(16) unsigned short PS[64 * 64];   //  8 KB [l][r], wave-private
    // total 40 KB -> 4 blocks/CU

    const int tid = threadIdx.x;
    const int wave = tid >> 6, lane = tid & 63;
    const int lr = lane & 15, lg = lane >> 4;
    const int l0 = blockIdx.x * 64;
    const int h = blockIdx.y, b = blockIdx.z;
    const size_t bh = (size_t)b * 16 + h;

    // Q A-fragments (pre-scaled by 1/8): rows 16*wave + lr, k = kh*32 + lg*8 + i
    bf16x8 qh[2], ql[2];
    {
        size_t base = (bh * 1024 + l0 + wave * 16 + lr) * 64 + lg * 8;
        qh[0] = *(const bf16x8*)&Qhi[base];
        qh[1] = *(const bf16x8*)&Qhi[base + 32];
        ql[0] = *(const bf16x8*)&Qlo[base];
        ql[1] = *(const bf16x8*)&Qlo[base + 32];
    }

    const f32x4 fzero = {0.f, 0.f, 0.f, 0.f};
    f32x4 oacc[4];
#pragma unroll
    for (int dt = 0; dt < 4; ++dt) oacc[dt] = fzero;
    float l_r[4] = {0.f, 0.f, 0.f, 0.f};   // per-lane partial denominators

    const int rowbase = wave * 16 + lg * 4;

    int cur = 0;
    for (int r0 = 0; r0 < 1024; r0 += 64, cur ^= 1) {
        unsigned short* bb16 = (unsigned short*)bbS[cur];

        // ---- S = Q K^T (split bf16, fp32 acc); K fragments direct from L2
        f32x4 sacc[4];
#pragma unroll
        for (int tt = 0; tt < 4; ++tt) {
            sacc[tt] = fzero;
            int rl = tt * 16 + lr;
            const unsigned short* krow = &Khi[(bh * 1024 + r0 + rl) * 64];
            const unsigned short* lrow = &Klo[(bh * 1024 + r0 + rl) * 64];
#pragma unroll
            for (int kh = 0; kh < 2; ++kh) {
                bf16x8 kf = *(const bf16x8*)&krow[kh * 32 + lg * 8];
                bf16x8 lf = *(const bf16x8*)&lrow[kh * 32 + lg * 8];
                sacc[tt] = MFMA16(qh[kh], kf, sacc[tt]);
                sacc[tt] = MFMA16(ql[kh], kf, sacc[tt]);
                sacc[tt] = MFMA16(qh[kh], lf, sacc[tt]);
            }
        }

        // ---- C = Q*PE^T, D = K*PE^T over 8 strips; PE + K-A-frags direct from L2
        bf16x8 ka[2];
        {
            const unsigned short* krow = &Khi[(bh * 1024 + r0 + wave * 16 + lr) * 64];
            ka[0] = *(const bf16x8*)&krow[lg * 8];
            ka[1] = *(const bf16x8*)&krow[32 + lg * 8];
        }
        const int tb = l0 - r0 + 960;          // window base in [0,1920]
#pragma unroll
        for (int tt = 0; tt < 8; ++tt) {
            int tl = tt * 16 + lr;
            int rg = tb + tl; if (rg > 2046) rg = 2046;   // clamped rows never stored
            f32x4 cacc = fzero, dacc = fzero;
#pragma unroll
            for (int kh = 0; kh < 2; ++kh) {
                bf16x8 pf = *(const bf16x8*)&de16[(size_t)rg * 64 + kh * 32 + lg * 8];
                cacc = MFMA16(qh[kh], pf, cacc);   // scaled via qh
                dacc = MFMA16(ka[kh], pf, dacc);   // unscaled; scale at store
            }
#pragma unroll
            for (int reg = 0; reg < 4; ++reg) {
                int row = rowbase + reg;
                int rl_c = row + 63 - tl;          // C: store iff 0..63
                if ((unsigned)rl_c < 64u)
                    bb16[2 * (row * 64 + (rl_c ^ (((row >> 2) & 3) << 3)))] = f2bf(cacc[reg]);
                int ll_d = tl + row - 63;          // D: store iff 0..63
                if ((unsigned)ll_d < 64u)
                    bb16[2 * (ll_d * 64 + (row ^ (((ll_d >> 2) & 3) << 3))) + 1]
                        = f2bf(dacc[reg] * SCALE);
            }
        }
        __syncthreads();   // the ONLY barrier: bands visible (D is cross-wave)

        // ---- gather + exp (no max-shift; denominator deferred to epilogue)
        float mask_v[4];
#pragma unroll
        for (int tt = 0; tt < 4; ++tt) mask_v[tt] = mask[b * 1024 + r0 + tt * 16 + lr];
#pragma unroll
        for (int reg = 0; reg < 4; ++reg) {
            int ll = rowbase + reg;
#pragma unroll
            for (int tt = 0; tt < 4; ++tt) {
                int rl = tt * 16 + lr;
                unsigned cd = bbS[cur][ll * 64 + (rl ^ (((ll >> 2) & 3) << 3))];
                float cg = __builtin_bit_cast(float, cd << 16);
                float dg = __builtin_bit_cast(float, cd & 0xFFFF0000u);
                float p = __expf(sacc[tt][reg] + cg + dg + mask_v[tt]);
                l_r[reg] += p;
                PS[ll * 64 + (((rl >> 3) ^ (ll & 7)) << 3) + (rl & 7)] = f2bf(p);
            }
        }

        // ---- PV: O += P V (unnormalized); P from wave-private LDS, V direct from L2
        {
            int alr = wave * 16 + lr;
#pragma unroll
            for (int kh = 0; kh < 2; ++kh) {
                int usa = (kh * 4 + lg) ^ (alr & 7);
                bf16x8 pa = *(const bf16x8*)&PS[alr * 64 + usa * 8];
#pragma unroll
                for (int dt = 0; dt < 4; ++dt) {
                    int dl = dt * 16 + lr;
                    bf16x8 vf = *(const bf16x8*)&Vt[(bh * 64 + dl) * 1024 + r0 + kh * 32 + lg * 8];
                    oacc[dt] = MFMA16(pa, vf, oacc[dt]);
                }
            }
        }
    }

    // ---- epilogue: reduce denominators across the 16 lr lanes, then divide
    float inv[4];
#pragma unroll
    for (int reg = 0; reg < 4; ++reg) {
        float s = l_r[reg];
        s += __shfl_xor(s, 1);
        s += __shfl_xor(s, 2);
        s += __shfl_xor(s, 4);
        s += __shfl_xor(s, 8);
        inv[reg] = 1.0f / s;
    }
#pragma unroll
    for (int dt = 0; dt < 4; ++dt)
#pragma unroll
        for (int reg = 0; reg < 4; ++reg) {
            int ll = wave * 16 + lg * 4 + reg;
            int dl = dt * 16 + lr;
            out[((size_t)b * 1024 + l0 + ll) * 1024 + h * 64 + dl] = oacc[dt][reg] * inv[reg];
        }
}

extern "C" void kernel_launch(void* const* d_in, const int* in_sizes, int n_in,
                              void* d_out, int out_size, void* d_ws, size_t ws_size,
                              hipStream_t stream) {
    const float* hs   = (const float*)d_in[0];
    const float* mask = (const float*)d_in[1];
    const float* Wq   = (const float*)d_in[2];
    const float* bq   = (const float*)d_in[3];
    const float* Wk   = (const float*)d_in[4];
    const float* bk   = (const float*)d_in[5];
    const float* Wv   = (const float*)d_in[6];
    const float* bv   = (const float*)d_in[7];
    const float* de   = (const float*)d_in[8];
    float* out = (float*)d_out;

    const size_t per = (size_t)4 * 16 * 1024 * 64;   // 4.19M elems (= 4096*1024)
    unsigned short* Qhi  = (unsigned short*)d_ws;
    unsigned short* Qlo  = Qhi + per;
    unsigned short* Khi  = Qlo + per;
    unsigned short* Klo  = Khi + per;
    unsigned short* Vtb  = Klo + per;
    unsigned short* Xhi  = Vtb + per;
    unsigned short* Xlo  = Xhi + per;
    unsigned short* Wthi = Xlo + per;
    unsigned short* Wtlo = Wthi + (size_t)3072 * 1024;
    unsigned short* de16 = Wtlo + (size_t)3072 * 1024;

    conv_x<<<2048, 256, 0, stream>>>(hs, Xhi, Xlo);
    conv_w<<<dim3(16, 16, 3), 256, 0, stream>>>(Wq, Wk, Wv, Wthi, Wtlo);
    conv_de<<<64, 256, 0, stream>>>(de, de16);

    qkv_gemm<<<dim3(24, 32), 256, 0, stream>>>(Xhi, Xlo, Wthi, Wtlo, bq, bk, bv,
                                               Qhi, Qlo, Khi, Klo, Vtb);

    dim3 agrid(16, 16, 4);
    attn_kernel<<<agrid, 256, 0, stream>>>(Qhi, Qlo, Khi, Klo, Vtb, de16, mask, out);
}

// Round 13
// 295.817 us; speedup vs baseline: 1.9268x; 1.9268x over previous
//
#include <hip/hip_runtime.h>

// B=4, H=16, L=1024, D=1024, DH=64, P=1024
// ws: Qhi,Qlo (pre-scaled by 1/8), Khi,Klo bf16 [B,H,L,64]; Vt bf16 [B,H,64,L];
//     Xhi,Xlo bf16 [4096,1024]; Wthi,Wtlo bf16 [3072,1024]; de16 bf16 [2047,64]

#define SCALE 0.125f  // 1/sqrt(64)

typedef __attribute__((ext_vector_type(8))) short bf16x8;
typedef __attribute__((ext_vector_type(4))) float f32x4;
#define MFMA16(a, b, c) __builtin_amdgcn_mfma_f32_16x16x32_bf16(a, b, c, 0, 0, 0)

__device__ __forceinline__ unsigned short f2bf(float x) {
    unsigned u = __builtin_bit_cast(unsigned, x);
    return (unsigned short)((u + 0x7FFFu + ((u >> 16) & 1u)) >> 16);  // RNE
}
__device__ __forceinline__ float bf2f(unsigned short h) {
    unsigned u = ((unsigned)h) << 16;
    return __builtin_bit_cast(float, u);
}

// ---------------- X fp32 -> hi/lo bf16 ----------------
__global__ __launch_bounds__(256) void conv_x(const float* __restrict__ x,
                                              unsigned short* __restrict__ xhi,
                                              unsigned short* __restrict__ xlo)
{
    size_t gid = (size_t)blockIdx.x * 256 + threadIdx.x;
    const float4* s = (const float4*)(x + gid * 8);
    float4 a = s[0], b = s[1];
    float v[8] = {a.x, a.y, a.z, a.w, b.x, b.y, b.z, b.w};
    unsigned hi[4], lo[4];
#pragma unroll
    for (int i = 0; i < 4; ++i) {
        unsigned short h0 = f2bf(v[2 * i]), h1 = f2bf(v[2 * i + 1]);
        hi[i] = (unsigned)h0 | ((unsigned)h1 << 16);
        unsigned short g0 = f2bf(v[2 * i] - bf2f(h0)), g1 = f2bf(v[2 * i + 1] - bf2f(h1));
        lo[i] = (unsigned)g0 | ((unsigned)g1 << 16);
    }
    *(uint4*)&xhi[gid * 8] = make_uint4(hi[0], hi[1], hi[2], hi[3]);
    *(uint4*)&xlo[gid * 8] = make_uint4(lo[0], lo[1], lo[2], lo[3]);
}

// ---------------- W [k][n] fp32 -> Wt [n + which*1024][k] hi/lo bf16 ----------------
__global__ __launch_bounds__(256) void conv_w(const float* __restrict__ Wq,
                                              const float* __restrict__ Wk,
                                              const float* __restrict__ Wv,
                                              unsigned short* __restrict__ wthi,
                                              unsigned short* __restrict__ wtlo)
{
    __shared__ float T[64][68];
    const int which = blockIdx.z;
    const float* W = which == 0 ? Wq : which == 1 ? Wk : Wv;
    const int k0 = blockIdx.y * 64, n0 = blockIdx.x * 64;
    const int ty = threadIdx.x >> 4, tx = threadIdx.x & 15;
#pragma unroll
    for (int i = 0; i < 4; ++i) {
        float4 v = *(const float4*)&W[(size_t)(k0 + ty * 4 + i) * 1024 + n0 + tx * 4];
        T[ty * 4 + i][tx * 4 + 0] = v.x;
        T[ty * 4 + i][tx * 4 + 1] = v.y;
        T[ty * 4 + i][tx * 4 + 2] = v.z;
        T[ty * 4 + i][tx * 4 + 3] = v.w;
    }
    __syncthreads();
#pragma unroll
    for (int i = 0; i < 4; ++i) {
        int n = n0 + ty * 4 + i;
        unsigned hi[2], lo[2];
#pragma unroll
        for (int p = 0; p < 2; ++p) {
            float v0 = T[tx * 4 + 2 * p][ty * 4 + i];
            float v1 = T[tx * 4 + 2 * p + 1][ty * 4 + i];
            unsigned short h0 = f2bf(v0), h1 = f2bf(v1);
            hi[p] = (unsigned)h0 | ((unsigned)h1 << 16);
            unsigned short g0 = f2bf(v0 - bf2f(h0)), g1 = f2bf(v1 - bf2f(h1));
            lo[p] = (unsigned)g0 | ((unsigned)g1 << 16);
        }
        size_t dst = (size_t)(which * 1024 + n) * 1024 + k0 + tx * 4;
        *(uint2*)&wthi[dst] = make_uint2(hi[0], hi[1]);
        *(uint2*)&wtlo[dst] = make_uint2(lo[0], lo[1]);
    }
}

// ---------------- dist_emb fp32 -> bf16 ----------------
__global__ __launch_bounds__(256) void conv_de(const float* __restrict__ de,
                                               unsigned short* __restrict__ de16)
{
    int gid = blockIdx.x * 256 + threadIdx.x;
    if (gid >= 16376) return;
    const float4* s = (const float4*)(de + gid * 8);
    float4 a = s[0], c = s[1];
    uint4 p;
    p.x = (unsigned)f2bf(a.x) | ((unsigned)f2bf(a.y) << 16);
    p.y = (unsigned)f2bf(a.z) | ((unsigned)f2bf(a.w) << 16);
    p.z = (unsigned)f2bf(c.x) | ((unsigned)f2bf(c.y) << 16);
    p.w = (unsigned)f2bf(c.z) | ((unsigned)f2bf(c.w) << 16);
    *(uint4*)&de16[gid * 8] = p;
}

// ---------------- fused QKV projection: split-bf16 MFMA GEMM ----------------
// T1: 1D grid 768, XCD-chunked decode — 3 n-tiles per XCD, Wt panels L2-resident.
__global__ __launch_bounds__(256, 2) void qkv_gemm(
    const unsigned short* __restrict__ Xhi, const unsigned short* __restrict__ Xlo,
    const unsigned short* __restrict__ Wthi, const unsigned short* __restrict__ Wtlo,
    const float* __restrict__ bq, const float* __restrict__ bk, const float* __restrict__ bv,
    unsigned short* __restrict__ Qhi, unsigned short* __restrict__ Qlo,
    unsigned short* __restrict__ Khi, unsigned short* __restrict__ Klo,
    unsigned short* __restrict__ Vt)
{
    __shared__ __align__(16) unsigned short AhiS[128 * 64];
    __shared__ __align__(16) unsigned short AloS[128 * 64];
    __shared__ __align__(16) unsigned short BhiS[128 * 64];
    __shared__ __align__(16) unsigned short BloS[128 * 64];

    const int tid = threadIdx.x;
    const int wave = tid >> 6, lane = tid & 63;
    const int lr = lane & 15, lg = lane >> 4;
    const int wr = wave >> 1, wc = wave & 1;
    // XCD-aware decode: hw id i runs on XCD i%8; give each XCD 3 n-columns x 32 m
    const int i = blockIdx.x;               // [0,768)
    const int xcd = i & 7, slot = i >> 3;   // slot in [0,96)
    const int n0 = (xcd * 3 + slot / 32) * 128;
    const int m0 = (slot & 31) * 128;

    const f32x4 fzero = {0.f, 0.f, 0.f, 0.f};
    f32x4 acc[4][4];
#pragma unroll
    for (int ii = 0; ii < 4; ++ii)
#pragma unroll
        for (int j = 0; j < 4; ++j) acc[ii][j] = fzero;

    for (int k0 = 0; k0 < 1024; k0 += 64) {
        __syncthreads();
#pragma unroll
        for (int t = 0; t < 4; ++t) {
            int idx = tid + t * 256;
            int r = idx >> 3, u = idx & 7;
            int us = u ^ (r & 7);
            *(uint4*)&AhiS[r * 64 + us * 8] = *(const uint4*)&Xhi[(size_t)(m0 + r) * 1024 + k0 + u * 8];
            *(uint4*)&AloS[r * 64 + us * 8] = *(const uint4*)&Xlo[(size_t)(m0 + r) * 1024 + k0 + u * 8];
            *(uint4*)&BhiS[r * 64 + us * 8] = *(const uint4*)&Wthi[(size_t)(n0 + r) * 1024 + k0 + u * 8];
            *(uint4*)&BloS[r * 64 + us * 8] = *(const uint4*)&Wtlo[(size_t)(n0 + r) * 1024 + k0 + u * 8];
        }
        __syncthreads();
#pragma unroll
        for (int kh = 0; kh < 2; ++kh) {
            bf16x8 ah[4], al[4], bh[4], bl[4];
#pragma unroll
            for (int ii = 0; ii < 4; ++ii) {
                int mrow = wr * 64 + ii * 16 + lr;
                int usa = (kh * 4 + lg) ^ (mrow & 7);
                ah[ii] = *(const bf16x8*)&AhiS[mrow * 64 + usa * 8];
                al[ii] = *(const bf16x8*)&AloS[mrow * 64 + usa * 8];
                int nrow = wc * 64 + ii * 16 + lr;
                int usb = (kh * 4 + lg) ^ (nrow & 7);
                bh[ii] = *(const bf16x8*)&BhiS[nrow * 64 + usb * 8];
                bl[ii] = *(const bf16x8*)&BloS[nrow * 64 + usb * 8];
            }
#pragma unroll
            for (int am = 0; am < 4; ++am)
#pragma unroll
                for (int bn = 0; bn < 4; ++bn) {
                    acc[am][bn] = MFMA16(ah[am], bh[bn], acc[am][bn]);
                    acc[am][bn] = MFMA16(al[am], bh[bn], acc[am][bn]);
                    acc[am][bn] = MFMA16(ah[am], bl[bn], acc[am][bn]);
                }
        }
    }

    const int which = n0 >> 10;
    const float* bsel = which == 0 ? bq : which == 1 ? bk : bv;
#pragma unroll
    for (int bn = 0; bn < 4; ++bn) {
        int n_g = n0 + wc * 64 + bn * 16 + lr;
        float bias = bsel[n_g & 1023];
        int hh = (n_g >> 6) & 15, d = n_g & 63;
#pragma unroll
        for (int am = 0; am < 4; ++am) {
#pragma unroll
            for (int reg = 0; reg < 4; ++reg) {
                int m_g = m0 + wr * 64 + am * 16 + lg * 4 + reg;
                int bb = m_g >> 10, l = m_g & 1023;
                float v = acc[am][bn][reg] + bias;
                if (which == 2) {
                    Vt[(((size_t)bb * 16 + hh) * 64 + d) * 1024 + l] = f2bf(v);
                } else {
                    if (which == 0) v *= SCALE;   // pre-scale Q (exact pow2)
                    size_t dst = (((size_t)bb * 16 + hh) * 1024 + l) * 64 + d;
                    unsigned short hi = f2bf(v);
                    unsigned short lo = f2bf(v - bf2f(hi));
                    if (which == 0) { Qhi[dst] = hi; Qlo[dst] = lo; }
                    else            { Khi[dst] = hi; Klo[dst] = lo; }
                }
            }
        }
    }
}

// ---------------- MFMA fused attention: round-7 body + T1 XCD group swizzle ----------
// Body byte-identical to the 221 us round-7 kernel (VGPR 112, 48 KB LDS, 2 blk/CU).
// Grid flattened to 1024; decode puts all 16 l-tiles of one (b,h) on ONE XCD with
// consecutive dispatch slots -> K/V fetched from HBM once per (b,h), L2-resident.
__global__ __launch_bounds__(256, 2) void attn_kernel(
    const unsigned short* __restrict__ Qhi, const unsigned short* __restrict__ Qlo,
    const unsigned short* __restrict__ Khi, const unsigned short* __restrict__ Klo,
    const unsigned short* __restrict__ Vt,  const unsigned short* __restrict__ de16,
    const float* __restrict__ mask, float* __restrict__ out)
{
    __shared__ __align__(16) unsigned short KhiS[64 * 64];   // 8 KB
    __shared__ __align__(16) unsigned short KloS[64 * 64];   // 8 KB
    __shared__ __align__(16) unsigned short VtS [64 * 64];   // 8 KB [d][r]
    __shared__ __align__(16) unsigned int   bbS [64 * 64];   // 16 KB [l][r]: lo=C, hi=D
    __shared__ __align__(16) unsigned short PS  [64 * 64];   // 8 KB [l][r]
    // total 48 KB

    const int tid = threadIdx.x;
    const int wave = tid >> 6, lane = tid & 63;
    const int lr = lane & 15, lg = lane >> 4;
    // T1 decode: hw id -> (group, member); XCD x hosts groups [x*8, x*8+8)
    const int i = blockIdx.x;               // [0,1024)
    const int xcd = i & 7, slot = i >> 3;   // slot in [0,128)
    const int g = xcd * 8 + (slot >> 4);    // (b,h) group in [0,64)
    const int l0 = (slot & 15) * 64;
    const int h = g & 15, b = g >> 4;
    const size_t bh = (size_t)b * 16 + h;
    unsigned short* bb16 = (unsigned short*)bbS;

    // Q A-fragments (pre-scaled by 1/8): rows 16*wave + lr, k = kh*32 + lg*8 + i
    bf16x8 qh[2], ql[2];
    {
        size_t base = (bh * 1024 + l0 + wave * 16 + lr) * 64 + lg * 8;
        qh[0] = *(const bf16x8*)&Qhi[base];
        qh[1] = *(const bf16x8*)&Qhi[base + 32];
        ql[0] = *(const bf16x8*)&Qlo[base];
        ql[1] = *(const bf16x8*)&Qlo[base + 32];
    }

    const f32x4 fzero = {0.f, 0.f, 0.f, 0.f};
    f32x4 oacc[4];
#pragma unroll
    for (int dt = 0; dt < 4; ++dt) oacc[dt] = fzero;
    float m_r[4], l_r[4];
#pragma unroll
    for (int r = 0; r < 4; ++r) { m_r[r] = -1e30f; l_r[r] = 0.f; }

    const int rowbase = wave * 16 + lg * 4;

    for (int r0 = 0; r0 < 1024; r0 += 64) {
        __syncthreads();   // prev-iter PV reads (PS, VtS) done before restaging
        // ---- stage K hi/lo [r][d] and Vt [d][r]
#pragma unroll
        for (int it = 0; it < 2; ++it) {
            int idx = tid + it * 256;          // 0..511
            int r = idx >> 3, u = idx & 7;
            int us = u ^ (r & 7);
            *(uint4*)&KhiS[r * 64 + us * 8] = *(const uint4*)&Khi[(bh * 1024 + r0 + r) * 64 + u * 8];
            *(uint4*)&KloS[r * 64 + us * 8] = *(const uint4*)&Klo[(bh * 1024 + r0 + r) * 64 + u * 8];
            *(uint4*)&VtS [r * 64 + us * 8] = *(const uint4*)&Vt [(bh * 64 + r) * 1024 + r0 + u * 8];
        }
        __syncthreads();

        // ---- S = Q K^T (split bf16, fp32 acc; already scaled via Q)
        f32x4 sacc[4];
#pragma unroll
        for (int tt = 0; tt < 4; ++tt) {
            sacc[tt] = fzero;
            int rl = tt * 16 + lr;
#pragma unroll
            for (int kh = 0; kh < 2; ++kh) {
                int us = (kh * 4 + lg) ^ (rl & 7);
                bf16x8 kf = *(const bf16x8*)&KhiS[rl * 64 + us * 8];
                bf16x8 lf = *(const bf16x8*)&KloS[rl * 64 + us * 8];
                sacc[tt] = MFMA16(qh[kh], kf, sacc[tt]);
                sacc[tt] = MFMA16(ql[kh], kf, sacc[tt]);
                sacc[tt] = MFMA16(qh[kh], lf, sacc[tt]);
            }
        }

        // ---- C = Q*PE^T, D = K*PE^T; band-only packed stores; PE direct from global
        bf16x8 ka[2];
        {
            int rl = wave * 16 + lr;
#pragma unroll
            for (int kh = 0; kh < 2; ++kh) {
                int us = (kh * 4 + lg) ^ (rl & 7);
                ka[kh] = *(const bf16x8*)&KhiS[rl * 64 + us * 8];
            }
        }
        const int tb = l0 - r0 + 960;          // window base in [0,1920]
#pragma unroll
        for (int tt = 0; tt < 8; ++tt) {
            int tl = tt * 16 + lr;
            int rg = tb + tl; if (rg > 2046) rg = 2046;   // tl=127 never used
            f32x4 cacc = fzero, dacc = fzero;
#pragma unroll
            for (int kh = 0; kh < 2; ++kh) {
                bf16x8 pf = *(const bf16x8*)&de16[(size_t)rg * 64 + kh * 32 + lg * 8];
                cacc = MFMA16(qh[kh], pf, cacc);   // scaled via qh
                dacc = MFMA16(ka[kh], pf, dacc);   // unscaled; scale at store
            }
#pragma unroll
            for (int reg = 0; reg < 4; ++reg) {
                int row = rowbase + reg;
                int rl_c = row + 63 - tl;          // C: store iff 0..63
                if ((unsigned)rl_c < 64u)
                    bb16[2 * (row * 64 + (rl_c ^ (((row >> 2) & 3) << 3)))] = f2bf(cacc[reg]);
                int ll_d = tl + row - 63;          // D: store iff 0..63
                if ((unsigned)ll_d < 64u)
                    bb16[2 * (ll_d * 64 + (row ^ (((ll_d >> 2) & 3) << 3))) + 1]
                        = f2bf(dacc[reg] * SCALE);
            }
        }
        __syncthreads();   // bands visible (D is cross-wave)

        // ---- gather + online softmax on accumulators
        float mask_v[4];
#pragma unroll
        for (int tt = 0; tt < 4; ++tt) mask_v[tt] = mask[b * 1024 + r0 + tt * 16 + lr];
#pragma unroll
        for (int reg = 0; reg < 4; ++reg) {
            int ll = rowbase + reg;
            float sv[4];
#pragma unroll
            for (int tt = 0; tt < 4; ++tt) {
                int rl = tt * 16 + lr;
                unsigned cd = bbS[ll * 64 + (rl ^ (((ll >> 2) & 3) << 3))];
                float cg = __builtin_bit_cast(float, cd << 16);
                float dg = __builtin_bit_cast(float, cd & 0xFFFF0000u);
                sv[tt] = sacc[tt][reg] + cg + dg + mask_v[tt];
            }
            float mx = fmaxf(fmaxf(sv[0], sv[1]), fmaxf(sv[2], sv[3]));
            mx = fmaxf(mx, __shfl_xor(mx, 1));
            mx = fmaxf(mx, __shfl_xor(mx, 2));
            mx = fmaxf(mx, __shfl_xor(mx, 4));
            mx = fmaxf(mx, __shfl_xor(mx, 8));
            float mnew = fmaxf(m_r[reg], mx);
            float a = __expf(m_r[reg] - mnew);
            float sum = 0.f;
#pragma unroll
            for (int tt = 0; tt < 4; ++tt) { sv[tt] = __expf(sv[tt] - mnew); sum += sv[tt]; }
            sum += __shfl_xor(sum, 1);
            sum += __shfl_xor(sum, 2);
            sum += __shfl_xor(sum, 4);
            sum += __shfl_xor(sum, 8);
            m_r[reg] = mnew;
            l_r[reg] = l_r[reg] * a + sum;
#pragma unroll
            for (int dt = 0; dt < 4; ++dt) oacc[dt][reg] *= a;
#pragma unroll
            for (int tt = 0; tt < 4; ++tt) {
                int rl = tt * 16 + lr;
                PS[ll * 64 + (((rl >> 3) ^ (ll & 7)) << 3) + (rl & 7)] = f2bf(sv[tt]);
            }
        }
        __syncthreads();   // P ready

        // ---- PV: O += P V
        {
            int alr = wave * 16 + lr;
#pragma unroll
            for (int kh = 0; kh < 2; ++kh) {
                int usa = (kh * 4 + lg) ^ (alr & 7);
                bf16x8 pa = *(const bf16x8*)&PS[alr * 64 + usa * 8];
#pragma unroll
                for (int dt = 0; dt < 4; ++dt) {
                    int dl = dt * 16 + lr;
                    int usb = (kh * 4 + lg) ^ (dl & 7);
                    bf16x8 vf = *(const bf16x8*)&VtS[dl * 64 + usb * 8];
                    oacc[dt] = MFMA16(pa, vf, oacc[dt]);
                }
            }
        }
    }

    // ---- epilogue: out[b, l, h*64+d] = O / l
    float inv[4];
#pragma unroll
    for (int reg = 0; reg < 4; ++reg) inv[reg] = 1.0f / l_r[reg];
#pragma unroll
    for (int dt = 0; dt < 4; ++dt)
#pragma unroll
        for (int reg = 0; reg < 4; ++reg) {
            int ll = wave * 16 + lg * 4 + reg;
            int dl = dt * 16 + lr;
            out[((size_t)b * 1024 + l0 + ll) * 1024 + h * 64 + dl] = oacc[dt][reg] * inv[reg];
        }
}

extern "C" void kernel_launch(void* const* d_in, const int* in_sizes, int n_in,
                              void* d_out, int out_size, void* d_ws, size_t ws_size,
                              hipStream_t stream) {
    const float* hs   = (const float*)d_in[0];
    const float* mask = (const float*)d_in[1];
    const float* Wq   = (const float*)d_in[2];
    const float* bq   = (const float*)d_in[3];
    const float* Wk   = (const float*)d_in[4];
    const float* bk   = (const float*)d_in[5];
    const float* Wv   = (const float*)d_in[6];
    const float* bv   = (const float*)d_in[7];
    const float* de   = (const float*)d_in[8];
    float* out = (float*)d_out;

    const size_t per = (size_t)4 * 16 * 1024 * 64;   // 4.19M elems (= 4096*1024)
    unsigned short* Qhi  = (unsigned short*)d_ws;
    unsigned short* Qlo  = Qhi + per;
    unsigned short* Khi  = Qlo + per;
    unsigned short* Klo  = Khi + per;
    unsigned short* Vtb  = Klo + per;
    unsigned short* Xhi  = Vtb + per;
    unsigned short* Xlo  = Xhi + per;
    unsigned short* Wthi = Xlo + per;
    unsigned short* Wtlo = Wthi + (size_t)3072 * 1024;
    unsigned short* de16 = Wtlo + (size_t)3072 * 1024;

    conv_x<<<2048, 256, 0, stream>>>(hs, Xhi, Xlo);
    conv_w<<<dim3(16, 16, 3), 256, 0, stream>>>(Wq, Wk, Wv, Wthi, Wtlo);
    conv_de<<<64, 256, 0, stream>>>(de, de16);

    qkv_gemm<<<768, 256, 0, stream>>>(Xhi, Xlo, Wthi, Wtlo, bq, bk, bv,
                                      Qhi, Qlo, Khi, Klo, Vtb);

    attn_kernel<<<1024, 256, 0, stream>>>(Qhi, Qlo, Khi, Klo, Vtb, de16, mask, out);
}

// Round 14
// 290.413 us; speedup vs baseline: 1.9626x; 1.0186x over previous
//
#include <hip/hip_runtime.h>

// B=4, H=16, L=1024, D=1024, DH=64, P=1024
// ws: Qhi,Qlo (pre-scaled by 1/8), Khi,Klo bf16 [B,H,L,64]; Vt bf16 [B,H,64,L];
//     Xhi,Xlo bf16 [4096,1024]; Wthi,Wtlo bf16 [3072,1024]; de16 bf16 [2047,64]

#define SCALE 0.125f  // 1/sqrt(64)

typedef __attribute__((ext_vector_type(8))) short bf16x8;
typedef __attribute__((ext_vector_type(4))) float f32x4;
#define MFMA16(a, b, c) __builtin_amdgcn_mfma_f32_16x16x32_bf16(a, b, c, 0, 0, 0)

__device__ __forceinline__ unsigned short f2bf(float x) {
    unsigned u = __builtin_bit_cast(unsigned, x);
    return (unsigned short)((u + 0x7FFFu + ((u >> 16) & 1u)) >> 16);  // RNE
}
__device__ __forceinline__ float bf2f(unsigned short h) {
    unsigned u = ((unsigned)h) << 16;
    return __builtin_bit_cast(float, u);
}

// ---------------- X fp32 -> hi/lo bf16 ----------------
__global__ __launch_bounds__(256) void conv_x(const float* __restrict__ x,
                                              unsigned short* __restrict__ xhi,
                                              unsigned short* __restrict__ xlo)
{
    size_t gid = (size_t)blockIdx.x * 256 + threadIdx.x;
    const float4* s = (const float4*)(x + gid * 8);
    float4 a = s[0], b = s[1];
    float v[8] = {a.x, a.y, a.z, a.w, b.x, b.y, b.z, b.w};
    unsigned hi[4], lo[4];
#pragma unroll
    for (int i = 0; i < 4; ++i) {
        unsigned short h0 = f2bf(v[2 * i]), h1 = f2bf(v[2 * i + 1]);
        hi[i] = (unsigned)h0 | ((unsigned)h1 << 16);
        unsigned short g0 = f2bf(v[2 * i] - bf2f(h0)), g1 = f2bf(v[2 * i + 1] - bf2f(h1));
        lo[i] = (unsigned)g0 | ((unsigned)g1 << 16);
    }
    *(uint4*)&xhi[gid * 8] = make_uint4(hi[0], hi[1], hi[2], hi[3]);
    *(uint4*)&xlo[gid * 8] = make_uint4(lo[0], lo[1], lo[2], lo[3]);
}

// ---------------- W [k][n] fp32 -> Wt [n + which*1024][k] hi/lo bf16 ----------------
__global__ __launch_bounds__(256) void conv_w(const float* __restrict__ Wq,
                                              const float* __restrict__ Wk,
                                              const float* __restrict__ Wv,
                                              unsigned short* __restrict__ wthi,
                                              unsigned short* __restrict__ wtlo)
{
    __shared__ float T[64][68];
    const int which = blockIdx.z;
    const float* W = which == 0 ? Wq : which == 1 ? Wk : Wv;
    const int k0 = blockIdx.y * 64, n0 = blockIdx.x * 64;
    const int ty = threadIdx.x >> 4, tx = threadIdx.x & 15;
#pragma unroll
    for (int i = 0; i < 4; ++i) {
        float4 v = *(const float4*)&W[(size_t)(k0 + ty * 4 + i) * 1024 + n0 + tx * 4];
        T[ty * 4 + i][tx * 4 + 0] = v.x;
        T[ty * 4 + i][tx * 4 + 1] = v.y;
        T[ty * 4 + i][tx * 4 + 2] = v.z;
        T[ty * 4 + i][tx * 4 + 3] = v.w;
    }
    __syncthreads();
#pragma unroll
    for (int i = 0; i < 4; ++i) {
        int n = n0 + ty * 4 + i;
        unsigned hi[2], lo[2];
#pragma unroll
        for (int p = 0; p < 2; ++p) {
            float v0 = T[tx * 4 + 2 * p][ty * 4 + i];
            float v1 = T[tx * 4 + 2 * p + 1][ty * 4 + i];
            unsigned short h0 = f2bf(v0), h1 = f2bf(v1);
            hi[p] = (unsigned)h0 | ((unsigned)h1 << 16);
            unsigned short g0 = f2bf(v0 - bf2f(h0)), g1 = f2bf(v1 - bf2f(h1));
            lo[p] = (unsigned)g0 | ((unsigned)g1 << 16);
        }
        size_t dst = (size_t)(which * 1024 + n) * 1024 + k0 + tx * 4;
        *(uint2*)&wthi[dst] = make_uint2(hi[0], hi[1]);
        *(uint2*)&wtlo[dst] = make_uint2(lo[0], lo[1]);
    }
}

// ---------------- dist_emb fp32 -> bf16 ----------------
__global__ __launch_bounds__(256) void conv_de(const float* __restrict__ de,
                                               unsigned short* __restrict__ de16)
{
    int gid = blockIdx.x * 256 + threadIdx.x;
    if (gid >= 16376) return;
    const float4* s = (const float4*)(de + gid * 8);
    float4 a = s[0], c = s[1];
    uint4 p;
    p.x = (unsigned)f2bf(a.x) | ((unsigned)f2bf(a.y) << 16);
    p.y = (unsigned)f2bf(a.z) | ((unsigned)f2bf(a.w) << 16);
    p.z = (unsigned)f2bf(c.x) | ((unsigned)f2bf(c.y) << 16);
    p.w = (unsigned)f2bf(c.z) | ((unsigned)f2bf(c.w) << 16);
    *(uint4*)&de16[gid * 8] = p;
}

// ---------------- fused QKV projection: split-bf16 MFMA GEMM ----------------
// T1: 1D grid 768, XCD-chunked decode — 3 n-tiles per XCD, Wt panels L2-resident.
__global__ __launch_bounds__(256, 2) void qkv_gemm(
    const unsigned short* __restrict__ Xhi, const unsigned short* __restrict__ Xlo,
    const unsigned short* __restrict__ Wthi, const unsigned short* __restrict__ Wtlo,
    const float* __restrict__ bq, const float* __restrict__ bk, const float* __restrict__ bv,
    unsigned short* __restrict__ Qhi, unsigned short* __restrict__ Qlo,
    unsigned short* __restrict__ Khi, unsigned short* __restrict__ Klo,
    unsigned short* __restrict__ Vt)
{
    __shared__ __align__(16) unsigned short AhiS[128 * 64];
    __shared__ __align__(16) unsigned short AloS[128 * 64];
    __shared__ __align__(16) unsigned short BhiS[128 * 64];
    __shared__ __align__(16) unsigned short BloS[128 * 64];

    const int tid = threadIdx.x;
    const int wave = tid >> 6, lane = tid & 63;
    const int lr = lane & 15, lg = lane >> 4;
    const int wr = wave >> 1, wc = wave & 1;
    const int i = blockIdx.x;               // [0,768)
    const int xcd = i & 7, slot = i >> 3;   // slot in [0,96)
    const int n0 = (xcd * 3 + slot / 32) * 128;
    const int m0 = (slot & 31) * 128;

    const f32x4 fzero = {0.f, 0.f, 0.f, 0.f};
    f32x4 acc[4][4];
#pragma unroll
    for (int ii = 0; ii < 4; ++ii)
#pragma unroll
        for (int j = 0; j < 4; ++j) acc[ii][j] = fzero;

    for (int k0 = 0; k0 < 1024; k0 += 64) {
        __syncthreads();
#pragma unroll
        for (int t = 0; t < 4; ++t) {
            int idx = tid + t * 256;
            int r = idx >> 3, u = idx & 7;
            int us = u ^ (r & 7);
            *(uint4*)&AhiS[r * 64 + us * 8] = *(const uint4*)&Xhi[(size_t)(m0 + r) * 1024 + k0 + u * 8];
            *(uint4*)&AloS[r * 64 + us * 8] = *(const uint4*)&Xlo[(size_t)(m0 + r) * 1024 + k0 + u * 8];
            *(uint4*)&BhiS[r * 64 + us * 8] = *(const uint4*)&Wthi[(size_t)(n0 + r) * 1024 + k0 + u * 8];
            *(uint4*)&BloS[r * 64 + us * 8] = *(const uint4*)&Wtlo[(size_t)(n0 + r) * 1024 + k0 + u * 8];
        }
        __syncthreads();
#pragma unroll
        for (int kh = 0; kh < 2; ++kh) {
            bf16x8 ah[4], al[4], bh[4], bl[4];
#pragma unroll
            for (int ii = 0; ii < 4; ++ii) {
                int mrow = wr * 64 + ii * 16 + lr;
                int usa = (kh * 4 + lg) ^ (mrow & 7);
                ah[ii] = *(const bf16x8*)&AhiS[mrow * 64 + usa * 8];
                al[ii] = *(const bf16x8*)&AloS[mrow * 64 + usa * 8];
                int nrow = wc * 64 + ii * 16 + lr;
                int usb = (kh * 4 + lg) ^ (nrow & 7);
                bh[ii] = *(const bf16x8*)&BhiS[nrow * 64 + usb * 8];
                bl[ii] = *(const bf16x8*)&BloS[nrow * 64 + usb * 8];
            }
#pragma unroll
            for (int am = 0; am < 4; ++am)
#pragma unroll
                for (int bn = 0; bn < 4; ++bn) {
                    acc[am][bn] = MFMA16(ah[am], bh[bn], acc[am][bn]);
                    acc[am][bn] = MFMA16(al[am], bh[bn], acc[am][bn]);
                    acc[am][bn] = MFMA16(ah[am], bl[bn], acc[am][bn]);
                }
        }
    }

    const int which = n0 >> 10;
    const float* bsel = which == 0 ? bq : which == 1 ? bk : bv;
#pragma unroll
    for (int bn = 0; bn < 4; ++bn) {
        int n_g = n0 + wc * 64 + bn * 16 + lr;
        float bias = bsel[n_g & 1023];
        int hh = (n_g >> 6) & 15, d = n_g & 63;
#pragma unroll
        for (int am = 0; am < 4; ++am) {
#pragma unroll
            for (int reg = 0; reg < 4; ++reg) {
                int m_g = m0 + wr * 64 + am * 16 + lg * 4 + reg;
                int bb = m_g >> 10, l = m_g & 1023;
                float v = acc[am][bn][reg] + bias;
                if (which == 2) {
                    Vt[(((size_t)bb * 16 + hh) * 64 + d) * 1024 + l] = f2bf(v);
                } else {
                    if (which == 0) v *= SCALE;   // pre-scale Q (exact pow2)
                    size_t dst = (((size_t)bb * 16 + hh) * 1024 + l) * 64 + d;
                    unsigned short hi = f2bf(v);
                    unsigned short lo = f2bf(v - bf2f(hi));
                    if (which == 0) { Qhi[dst] = hi; Qlo[dst] = lo; }
                    else            { Khi[dst] = hi; Klo[dst] = lo; }
                }
            }
        }
    }
}

// ---------------- MFMA fused attention: 2-barrier dbuf loop + T1 swizzle ----------------
// r13 base (XCD group swizzle, FETCH=21.6MB proven) with:
//  - K/V double-buffered -> loop-top barrier eliminated; stage is inline load->write
//    placed AFTER the bands barrier so HBM/L2 latency hides under gather+PV (T14),
//    temps live only inside the stage block (r9/r11 spill lesson).
//  - PS barrier eliminated (wave-private rows, r12-validated).
//  - no-max softmax, denominator deferred to epilogue (r9/r10-validated).
//  - C strips [w,w+4], D strips [3-w,7-w]: 20 MFMA/iter vs 32 (r9-validated).
// 2 __syncthreads per KV tile (was 4). LDS 72 KB -> 2 blocks/CU.
__global__ __launch_bounds__(256, 2) void attn_kernel(
    const unsigned short* __restrict__ Qhi, const unsigned short* __restrict__ Qlo,
    const unsigned short* __restrict__ Khi, const unsigned short* __restrict__ Klo,
    const unsigned short* __restrict__ Vt,  const unsigned short* __restrict__ de16,
    const float* __restrict__ mask, float* __restrict__ out)
{
    __shared__ __align__(16) unsigned short KhiS[2][64 * 64];   // 16 KB
    __shared__ __align__(16) unsigned short KloS[2][64 * 64];   // 16 KB
    __shared__ __align__(16) unsigned short VtS [2][64 * 64];   // 16 KB [d][r]
    __shared__ __align__(16) unsigned int   bbS [64 * 64];      // 16 KB [l][r]: lo=C, hi=D
    __shared__ __align__(16) unsigned short PS  [64 * 64];      //  8 KB [l][r], wave-private
    // total 72 KB -> 2 blocks/CU

    const int tid = threadIdx.x;
    const int wave = tid >> 6, lane = tid & 63;
    const int lr = lane & 15, lg = lane >> 4;
    // T1 decode: hw id -> (group, member); XCD x hosts groups [x*8, x*8+8)
    const int i = blockIdx.x;               // [0,1024)
    const int xcd = i & 7, slot = i >> 3;   // slot in [0,128)
    const int g = xcd * 8 + (slot >> 4);    // (b,h) group in [0,64)
    const int l0 = (slot & 15) * 64;
    const int h = g & 15, b = g >> 4;
    const size_t bh = (size_t)b * 16 + h;
    unsigned short* bb16 = (unsigned short*)bbS;

    // Q A-fragments (pre-scaled by 1/8): rows 16*wave + lr, k = kh*32 + lg*8 + i
    bf16x8 qh[2], ql[2];
    {
        size_t base = (bh * 1024 + l0 + wave * 16 + lr) * 64 + lg * 8;
        qh[0] = *(const bf16x8*)&Qhi[base];
        qh[1] = *(const bf16x8*)&Qhi[base + 32];
        ql[0] = *(const bf16x8*)&Qlo[base];
        ql[1] = *(const bf16x8*)&Qlo[base + 32];
    }

    // staging coords: 2 uint4 rows per thread per buffer (rows sr0, sr0+32)
    const int sr0 = tid >> 3, su = tid & 7;
    auto stage = [&](int r0s, int buf) {
        uint4 t_kh[2], t_kl[2], t_vt[2];
#pragma unroll
        for (int it = 0; it < 2; ++it) {
            int r = sr0 + it * 32;
            t_kh[it] = *(const uint4*)&Khi[(bh * 1024 + r0s + r) * 64 + su * 8];
            t_kl[it] = *(const uint4*)&Klo[(bh * 1024 + r0s + r) * 64 + su * 8];
            t_vt[it] = *(const uint4*)&Vt [(bh * 64 + r) * 1024 + r0s + su * 8];
        }
#pragma unroll
        for (int it = 0; it < 2; ++it) {
            int r = sr0 + it * 32;
            int us = su ^ (r & 7);
            *(uint4*)&KhiS[buf][r * 64 + us * 8] = t_kh[it];
            *(uint4*)&KloS[buf][r * 64 + us * 8] = t_kl[it];
            *(uint4*)&VtS [buf][r * 64 + us * 8] = t_vt[it];
        }
    };

    // ---- prologue: stage tile 0 into buffer 0
    stage(0, 0);
    __syncthreads();

    const f32x4 fzero = {0.f, 0.f, 0.f, 0.f};
    f32x4 oacc[4];
#pragma unroll
    for (int dt = 0; dt < 4; ++dt) oacc[dt] = fzero;
    float l_r[4] = {0.f, 0.f, 0.f, 0.f};   // per-lane partial denominators

    const int rowbase = wave * 16 + lg * 4;

    for (int it16 = 0; it16 < 16; ++it16) {
        const int r0 = it16 * 64;
        const int cur = it16 & 1;
        const unsigned short* KhiC = KhiS[cur];
        const unsigned short* KloC = KloS[cur];
        const unsigned short* VtC  = VtS[cur];

        // ---- S = Q K^T (split bf16, fp32 acc; pre-scaled via Q)
        f32x4 sacc[4];
#pragma unroll
        for (int tt = 0; tt < 4; ++tt) {
            sacc[tt] = fzero;
            int rl = tt * 16 + lr;
#pragma unroll
            for (int kh = 0; kh < 2; ++kh) {
                int us = (kh * 4 + lg) ^ (rl & 7);
                bf16x8 kf = *(const bf16x8*)&KhiC[rl * 64 + us * 8];
                bf16x8 lf = *(const bf16x8*)&KloC[rl * 64 + us * 8];
                sacc[tt] = MFMA16(qh[kh], kf, sacc[tt]);
                sacc[tt] = MFMA16(ql[kh], kf, sacc[tt]);
                sacc[tt] = MFMA16(qh[kh], lf, sacc[tt]);
            }
        }

        const int tb = l0 - r0 + 960;   // window base in [0,1920]

        // ---- C = Q*PE^T, strips [wave, wave+4] (exact band coverage)
#pragma unroll
        for (int c = 0; c < 5; ++c) {
            int tl = (wave + c) * 16 + lr;
            int rg = tb + tl; if (rg > 2046) rg = 2046;   // clamped rows never stored
            f32x4 cacc = fzero;
#pragma unroll
            for (int kh = 0; kh < 2; ++kh) {
                bf16x8 pfv = *(const bf16x8*)&de16[(size_t)rg * 64 + kh * 32 + lg * 8];
                cacc = MFMA16(qh[kh], pfv, cacc);
            }
#pragma unroll
            for (int reg = 0; reg < 4; ++reg) {
                int row = rowbase + reg;
                int rl_c = row + 63 - tl;
                if ((unsigned)rl_c < 64u)
                    bb16[2 * (row * 64 + (rl_c ^ (((row >> 2) & 3) << 3)))] = f2bf(cacc[reg]);
            }
        }

        // ---- D = K*PE^T, strips [3-wave, 7-wave]; A = own K rows
        bf16x8 ka[2];
        {
            int rl = wave * 16 + lr;
#pragma unroll
            for (int kh = 0; kh < 2; ++kh) {
                int us = (kh * 4 + lg) ^ (rl & 7);
                ka[kh] = *(const bf16x8*)&KhiC[rl * 64 + us * 8];
            }
        }
#pragma unroll
        for (int c = 0; c < 5; ++c) {
            int tl = (3 - wave + c) * 16 + lr;
            int rg = tb + tl; if (rg > 2046) rg = 2046;
            f32x4 dacc = fzero;
#pragma unroll
            for (int kh = 0; kh < 2; ++kh) {
                bf16x8 pfv = *(const bf16x8*)&de16[(size_t)rg * 64 + kh * 32 + lg * 8];
                dacc = MFMA16(ka[kh], pfv, dacc);
            }
#pragma unroll
            for (int reg = 0; reg < 4; ++reg) {
                int r_row = rowbase + reg;
                int ll_d = tl + r_row - 63;
                if ((unsigned)ll_d < 64u)
                    bb16[2 * (ll_d * 64 + (r_row ^ (((ll_d >> 2) & 3) << 3))) + 1]
                        = f2bf(dacc[reg] * SCALE);
            }
        }
        __syncthreads();   // BARRIER 1: bands visible (D cross-wave); prev gather done

        // ---- stage next tile into spare buffer (loads overlap gather+PV below;
        //      safe: PV(i-1) reads of buf[cur^1] finished before the PREVIOUS barrier)
        if (it16 < 15) stage(r0 + 64, cur ^ 1);

        // ---- gather + exp (no max-shift; denominator deferred to epilogue)
        float mask_v[4];
#pragma unroll
        for (int tt = 0; tt < 4; ++tt) mask_v[tt] = mask[b * 1024 + r0 + tt * 16 + lr];
#pragma unroll
        for (int reg = 0; reg < 4; ++reg) {
            int ll = rowbase + reg;
#pragma unroll
            for (int tt = 0; tt < 4; ++tt) {
                int rl = tt * 16 + lr;
                unsigned cd = bbS[ll * 64 + (rl ^ (((ll >> 2) & 3) << 3))];
                float cg = __builtin_bit_cast(float, cd << 16);
                float dg = __builtin_bit_cast(float, cd & 0xFFFF0000u);
                float p = __expf(sacc[tt][reg] + cg + dg + mask_v[tt]);
                l_r[reg] += p;
                PS[ll * 64 + (((rl >> 3) ^ (ll & 7)) << 3) + (rl & 7)] = f2bf(p);
            }
        }
        // (no barrier: PS rows are wave-private; intra-wave LDS order suffices — r12)

        // ---- PV: O += P V (unnormalized)
        {
            int alr = wave * 16 + lr;
#pragma unroll
            for (int kh = 0; kh < 2; ++kh) {
                int usa = (kh * 4 + lg) ^ (alr & 7);
                bf16x8 pa = *(const bf16x8*)&PS[alr * 64 + usa * 8];
#pragma unroll
                for (int dt = 0; dt < 4; ++dt) {
                    int dl = dt * 16 + lr;
                    int usb = (kh * 4 + lg) ^ (dl & 7);
                    bf16x8 vf = *(const bf16x8*)&VtC[dl * 64 + usb * 8];
                    oacc[dt] = MFMA16(pa, vf, oacc[dt]);
                }
            }
        }
        __syncthreads();   // BARRIER 2: staging done; next iter may read buf[cur^1]
    }

    // ---- epilogue: reduce denominators across the 16 lr lanes, then divide
    float inv[4];
#pragma unroll
    for (int reg = 0; reg < 4; ++reg) {
        float s = l_r[reg];
        s += __shfl_xor(s, 1);
        s += __shfl_xor(s, 2);
        s += __shfl_xor(s, 4);
        s += __shfl_xor(s, 8);
        inv[reg] = 1.0f / s;
    }
#pragma unroll
    for (int dt = 0; dt < 4; ++dt)
#pragma unroll
        for (int reg = 0; reg < 4; ++reg) {
            int ll = wave * 16 + lg * 4 + reg;
            int dl = dt * 16 + lr;
            out[((size_t)b * 1024 + l0 + ll) * 1024 + h * 64 + dl] = oacc[dt][reg] * inv[reg];
        }
}

extern "C" void kernel_launch(void* const* d_in, const int* in_sizes, int n_in,
                              void* d_out, int out_size, void* d_ws, size_t ws_size,
                              hipStream_t stream) {
    const float* hs   = (const float*)d_in[0];
    const float* mask = (const float*)d_in[1];
    const float* Wq   = (const float*)d_in[2];
    const float* bq   = (const float*)d_in[3];
    const float* Wk   = (const float*)d_in[4];
    const float* bk   = (const float*)d_in[5];
    const float* Wv   = (const float*)d_in[6];
    const float* bv   = (const float*)d_in[7];
    const float* de   = (const float*)d_in[8];
    float* out = (float*)d_out;

    const size_t per = (size_t)4 * 16 * 1024 * 64;   // 4.19M elems (= 4096*1024)
    unsigned short* Qhi  = (unsigned short*)d_ws;
    unsigned short* Qlo  = Qhi + per;
    unsigned short* Khi  = Qlo + per;
    unsigned short* Klo  = Khi + per;
    unsigned short* Vtb  = Klo + per;
    unsigned short* Xhi  = Vtb + per;
    unsigned short* Xlo  = Xhi + per;
    unsigned short* Wthi = Xlo + per;
    unsigned short* Wtlo = Wthi + (size_t)3072 * 1024;
    unsigned short* de16 = Wtlo + (size_t)3072 * 1024;

    conv_x<<<2048, 256, 0, stream>>>(hs, Xhi, Xlo);
    conv_w<<<dim3(16, 16, 3), 256, 0, stream>>>(Wq, Wk, Wv, Wthi, Wtlo);
    conv_de<<<64, 256, 0, stream>>>(de, de16);

    qkv_gemm<<<768, 256, 0, stream>>>(Xhi, Xlo, Wthi, Wtlo, bq, bk, bv,
                                      Qhi, Qlo, Khi, Klo, Vtb);

    attn_kernel<<<1024, 256, 0, stream>>>(Qhi, Qlo, Khi, Klo, Vtb, de16, mask, out);
}